// Round 3
// baseline (28.726 us; speedup 1.0000x reference)
//
#include <hip/hip_runtime.h>
#include <math.h>

// One WAVE (64 lanes) per proposal, 4 elements per lane, blocked layout:
// element e = lane*4 + r. Full bitonic sort of 256 radii:
//   - element strides 1,2  -> in-register compare-exchange (15 stages)
//   - element strides 4..128 -> lane strides 1..32 via __shfl_xor (21 stages)
// No LDS, no __syncthreads. min/median/max read from sorted positions;
// mean via butterfly shuffle reduce before the sort.

#define CX_LANE(K, J)                                                         \
    {                                                                         \
        const int  ls       = (J) >> 2;                                       \
        const bool keep_min = (((e0 & (K)) == 0) == ((e0 & (J)) == 0));       \
        _Pragma("unroll")                                                     \
        for (int r = 0; r < 4; ++r) {                                         \
            const float o  = __shfl_xor(v[r], ls, 64);                        \
            const float mn = fminf(v[r], o);                                  \
            const float mx = fmaxf(v[r], o);                                  \
            v[r] = keep_min ? mn : mx;                                        \
        }                                                                     \
    }

#define CX_REG2(K)                                                            \
    {                                                                         \
        const bool a = ((e0 & (K)) == 0);                                     \
        float mn = fminf(v[0], v[2]), mx = fmaxf(v[0], v[2]);                 \
        v[0] = a ? mn : mx; v[2] = a ? mx : mn;                               \
        mn = fminf(v[1], v[3]); mx = fmaxf(v[1], v[3]);                       \
        v[1] = a ? mn : mx; v[3] = a ? mx : mn;                               \
    }

#define CX_REG1(K)                                                            \
    {                                                                         \
        const bool a01 = (((e0 + 0) & (K)) == 0);                             \
        const bool a23 = (((e0 + 2) & (K)) == 0);                             \
        float mn = fminf(v[0], v[1]), mx = fmaxf(v[0], v[1]);                 \
        v[0] = a01 ? mn : mx; v[1] = a01 ? mx : mn;                           \
        mn = fminf(v[2], v[3]); mx = fmaxf(v[2], v[3]);                       \
        v[2] = a23 ? mn : mx; v[3] = a23 ? mx : mn;                           \
    }

__global__ __launch_bounds__(256) void offs4feat_kernel(
    const int*   __restrict__ prop_offset,   // (P+1,) int32
    const int*   __restrict__ prop_idx,      // (M,2)  int32, col 1 = point id
    const float* __restrict__ pt_offsets,    // (N,3)  f32
    const int*   __restrict__ npoint_ptr,    // scalar int32 (=256)
    float*       __restrict__ out,           // (P,4)  f32
    int n_props)
{
    const int t    = threadIdx.x;
    const int lane = t & 63;
    const int p    = blockIdx.x * 4 + (t >> 6);   // one wave per proposal
    if (p >= n_props) return;

    const int np    = *npoint_ptr;            // 256 in this harness
    const int start = prop_offset[p];
    const int e0    = lane << 2;               // first element index of this lane

    // ---- load 4 point ids (column 1 of prop_idx), coalesced ----
    int id[4];
    if (e0 + 3 < np) {
        const int* base = prop_idx + (size_t)(start + e0) * 2;
        const int2 a = *(const int2*)(base + 0);
        const int2 b = *(const int2*)(base + 2);
        const int2 c = *(const int2*)(base + 4);
        const int2 d = *(const int2*)(base + 6);
        id[0] = a.y; id[1] = b.y; id[2] = c.y; id[3] = d.y;
    } else {
        #pragma unroll
        for (int r = 0; r < 4; ++r) {
            int ei = e0 + r; ei = (ei < np) ? ei : (np - 1);   // clamp, stays in-bounds
            id[r] = prop_idx[(size_t)(start + ei) * 2 + 1];
        }
    }

    // ---- gather 4 points (issue all 12 loads before computing) ----
    float x[4], y[4], z[4];
    #pragma unroll
    for (int r = 0; r < 4; ++r) {
        const float* q = pt_offsets + (size_t)id[r] * 3;
        x[r] = q[0]; y[r] = q[1]; z[r] = q[2];
    }

    float v[4];
    float s = 0.0f;
    #pragma unroll
    for (int r = 0; r < 4; ++r) {
        const float rr = sqrtf(fmaf(x[r], x[r], fmaf(y[r], y[r], z[r] * z[r])));
        const bool act = (e0 + r) < np;
        s   += act ? rr : 0.0f;
        v[r] = act ? rr : INFINITY;            // pads sort to the tail
    }

    // ---- mean: butterfly reduce across the wave ----
    #pragma unroll
    for (int o = 32; o > 0; o >>= 1) s += __shfl_xor(s, o, 64);

    // ---- bitonic sort of 256 elements (blocked 4/lane) ----
    CX_REG1(2)
    CX_REG2(4)  CX_REG1(4)
    CX_LANE(8, 4)   CX_REG2(8)   CX_REG1(8)
    CX_LANE(16, 8)  CX_LANE(16, 4)  CX_REG2(16)  CX_REG1(16)
    CX_LANE(32, 16) CX_LANE(32, 8)  CX_LANE(32, 4)  CX_REG2(32)  CX_REG1(32)
    CX_LANE(64, 32) CX_LANE(64, 16) CX_LANE(64, 8)  CX_LANE(64, 4)
    CX_REG2(64)  CX_REG1(64)
    CX_LANE(128, 64) CX_LANE(128, 32) CX_LANE(128, 16) CX_LANE(128, 8)
    CX_LANE(128, 4)  CX_REG2(128) CX_REG1(128)
    CX_LANE(256, 128) CX_LANE(256, 64) CX_LANE(256, 32) CX_LANE(256, 16)
    CX_LANE(256, 8)   CX_LANE(256, 4)  CX_REG2(256) CX_REG1(256)
    // v[r] == sorted[lane*4 + r]

    // ---- writes ----
    const int emed = (np - 1) >> 1;            // 127
    const int emax = np - 1;                   // 255
    auto pick = [&](int rr_) {
        return rr_ == 0 ? v[0] : rr_ == 1 ? v[1] : rr_ == 2 ? v[2] : v[3];
    };
    if (lane == 0) {
        out[p * 4 + 0] = s / (float)np;        // mean
        out[p * 4 + 2] = v[0];                 // min = sorted[0]
    }
    if (lane == (emed >> 2)) out[p * 4 + 1] = pick(emed & 3);   // median
    if (lane == (emax >> 2)) out[p * 4 + 3] = pick(emax & 3);   // max
}

extern "C" void kernel_launch(void* const* d_in, const int* in_sizes, int n_in,
                              void* d_out, int out_size, void* d_ws, size_t ws_size,
                              hipStream_t stream) {
    // d_in order per setup_inputs():
    //   0: semantic_scores (f32, unused — output dtype only)
    //   1: proposals_offset (int32, P+1)
    //   2: proposals_idx    (int32, (M,2))
    //   3: pt_offsets       (f32,  (N,3))
    //   4: min_npoint       (int32 scalar)
    const int*   prop_offset = (const int*)  d_in[1];
    const int*   prop_idx    = (const int*)  d_in[2];
    const float* pt_offsets  = (const float*)d_in[3];
    const int*   npoint_ptr  = (const int*)  d_in[4];
    float*       out         = (float*)      d_out;

    const int n_proposals = in_sizes[1] - 1;   // 4096
    const int n_blocks    = (n_proposals + 3) / 4;

    offs4feat_kernel<<<n_blocks, 256, 0, stream>>>(
        prop_offset, prop_idx, pt_offsets, npoint_ptr, out, n_proposals);
}